// Round 6
// baseline (90.900 us; speedup 1.0000x reference)
//
#include <hip/hip_runtime.h>
#include <math.h>

// One wave per ray, 4 rays/block. R5-verified skeleton with two changes:
// (1) A/B staged in d_ws (global, wave-uniform float4 reads -> VMEM/L1 pipe)
//     instead of LDS broadcasts — takes 64 ds_read_b128 off the LDS pipe.
// (2) Packed fp32 (v_pk_fma_f32 / v_pk_max_f32) in both MLP loops.
// Scans, CDF, sampling, and the LDS-single-source-of-truth merge are
// byte-identical to R5 (bit-consistency is what R3/R4 violated).

#define RAYS   8192
#define NEARP  2.0f
#define FARP   6.0f
#define EPS_T  1e-10f
#define EPS_W  1e-5f
#define F32EPS 1.1920929e-7f

typedef float v2f __attribute__((ext_vector_type(2)));
__device__ __forceinline__ v2f mk2(float a, float b) { v2f r; r.x = a; r.y = b; return r; }
__device__ __forceinline__ v2f pfma(v2f a, v2f b, v2f c) { return __builtin_elementwise_fma(a, b, c); }
__device__ __forceinline__ v2f pmax0(v2f a) { return __builtin_elementwise_max(a, mk2(0.f, 0.f)); }

__device__ __forceinline__ float zc(int i) {
    const float t = (float)i * (1.0f / 63.0f);
    return NEARP * (1.0f - t) + FARP * t;
}
__device__ __forceinline__ float sigm(float x) { return 1.f / (1.f + __expf(-x)); }

__global__ __launch_bounds__(256) void nerf_kernel(
    const float* __restrict__ ro, const float* __restrict__ rd,
    const float* __restrict__ W1, const float* __restrict__ b1,
    const float* __restrict__ W2, const float* __restrict__ b2,
    float* __restrict__ out, float* __restrict__ ws)
{
    __shared__ float sCdf[4][64];    // 63 used
    __shared__ float sZc [4][64];    // coarse z grid (single source of truth for merge)
    __shared__ float sZs [4][128];   // fine z samples (sorted)
    __shared__ float sZf [4][192];   // merged

    const int tid  = threadIdx.x;
    const int w    = tid >> 6;
    const int lane = tid & 63;
    const int ray  = blockIdx.x * 4 + w;

    const float ox = ro[ray * 3 + 0], oy = ro[ray * 3 + 1], oz = ro[ray * 3 + 2];
    const float dx = rd[ray * 3 + 0], dy = rd[ray * 3 + 1], dz = rd[ray * 3 + 2];
    const float norm = sqrtf(dx * dx + dy * dy + dz * dz);
    const float inv  = 1.f / norm;
    const float vx = dx * inv, vy = dy * inv, vz = dz * inv;

    // ---- per-ray A/B precompute: lane h; staged in global ws (own-wave RAW) ----
    float* wsray = ws + (size_t)ray * 128;
    {
        const float w10 = W1[lane],       w11 = W1[64 + lane],  w12 = W1[128 + lane];
        const float w13 = W1[192 + lane], w14 = W1[256 + lane], w15 = W1[320 + lane];
        float A = b1[lane];
        A = fmaf(vz, w15, A); A = fmaf(vy, w14, A); A = fmaf(vx, w13, A);
        A = fmaf(oz, w12, A); A = fmaf(oy, w11, A); A = fmaf(ox, w10, A);
        const float B = fmaf(dx, w10, fmaf(dy, w11, dz * w12));
        wsray[lane] = A; wsray[64 + lane] = B;
    }
    __threadfence_block();
    const float4* ABa = (const float4*)wsray;          // A[4i..4i+3]
    const float4* ABb = (const float4*)(wsray + 64);   // B[4i..4i+3]

    const float4* W2v = (const float4*)W2;
    const float bb0 = b2[0], bb1 = b2[1], bb2 = b2[2], bb3 = b2[3];

    // ---------------- coarse pass ----------------
    const float z = zc(lane);
    sZc[w][lane] = z;
    const v2f zz = mk2(z, z);
    v2f o01 = mk2(bb0, bb1), o23 = mk2(bb2, bb3);
#pragma unroll 4
    for (int i = 0; i < 16; ++i) {
        const float4 a4 = ABa[i];
        const float4 b4 = ABb[i];
        const float4 q0 = W2v[4 * i + 0], q1 = W2v[4 * i + 1];
        const float4 q2 = W2v[4 * i + 2], q3 = W2v[4 * i + 3];
        const v2f hL = pmax0(pfma(zz, mk2(b4.x, b4.y), mk2(a4.x, a4.y)));
        const v2f hH = pmax0(pfma(zz, mk2(b4.z, b4.w), mk2(a4.z, a4.w)));
        o01 = pfma(mk2(hL.x, hL.x), mk2(q0.x, q0.y), o01);
        o23 = pfma(mk2(hL.x, hL.x), mk2(q0.z, q0.w), o23);
        o01 = pfma(mk2(hL.y, hL.y), mk2(q1.x, q1.y), o01);
        o23 = pfma(mk2(hL.y, hL.y), mk2(q1.z, q1.w), o23);
        o01 = pfma(mk2(hH.x, hH.x), mk2(q2.x, q2.y), o01);
        o23 = pfma(mk2(hH.x, hH.x), mk2(q2.z, q2.w), o23);
        o01 = pfma(mk2(hH.y, hH.y), mk2(q3.x, q3.y), o01);
        o23 = pfma(mk2(hH.y, hH.y), mk2(q3.z, q3.w), o23);
    }
    const float r   = sigm(o01.x), g = sigm(o01.y), bl = sigm(o23.x);
    const float sig = fmaxf(o23.y, 0.f);

    // volrender (coarse)
    const float znext = __shfl_down(z, 1);                 // lane63 unused
    const float dist  = (znext - z) * norm;
    const float alpha = (lane < 63) ? (1.f - __expf(-sig * dist)) : 1.f;
    const float vfac  = 1.f - alpha + EPS_T;
    float p = vfac;
#pragma unroll
    for (int off = 1; off < 64; off <<= 1) {               // inclusive product scan
        const float q = __shfl_up(p, off);
        if (lane >= off) p *= q;
    }
    float excl = __shfl_up(p, 1);
    if (lane == 0) excl = 1.f;
    const float wgt = alpha * excl;

    // acc == 1 + O(64*EPS_T) (last alpha forced 1) -> white-bkgd term ~0
    float sr = wgt * r, sg = wgt * g, sb = wgt * bl, sd = wgt * z;
#pragma unroll
    for (int m = 1; m < 64; m <<= 1) {
        sr += __shfl_xor(sr, m); sg += __shfl_xor(sg, m);
        sb += __shfl_xor(sb, m); sd += __shfl_xor(sd, m);
    }

    // ---------------- inverse-CDF sampling ----------------
    const float wmraw = __shfl_down(wgt, 1);
    const float wmv   = (lane < 62) ? wmraw : 0.f;          // weights[:,1:-1], 62 bins
    float wsum = wmv;
#pragma unroll
    for (int m = 1; m < 64; m <<= 1) wsum += __shfl_xor(wsum, m);
    const float pad  = fmaxf(0.f, EPS_W - wsum);
    const float wadj = wmv + pad * (1.0f / 62.0f);
    const float wsp  = wsum + pad;
    const float pdf  = (lane < 62) ? (wadj / wsp) : 0.f;
    float ps = pdf;
#pragma unroll
    for (int off = 1; off < 64; off <<= 1) {               // inclusive sum scan
        const float q = __shfl_up(ps, off);
        if (lane >= off) ps += q;
    }
    if (lane < 61)  sCdf[w][lane + 1] = fminf(1.f, ps);    // cdf[1..61]
    if (lane == 61) sCdf[w][0]  = 0.f;
    if (lane == 62) sCdf[w][62] = 1.f;
    __syncthreads();

    float zsv[2];
#pragma unroll
    for (int j = 0; j < 2; ++j) {
        const int f = lane * 2 + j;
        const float u = (float)f * ((1.0f - F32EPS) / 127.0f);
        int lo = 0, hi = 62;                               // cdf[0]=0<=u < 1=cdf[62]
        while (hi - lo > 1) {
            const int mid = (lo + hi) >> 1;
            if (sCdf[w][mid] <= u) lo = mid; else hi = mid;
        }
        const float c0 = sCdf[w][lo], c1 = sCdf[w][lo + 1];
        const float den = c1 - c0;
        float tt = (den > 0.f) ? (u - c0) / den : 0.f;
        tt = fminf(fmaxf(tt, 0.f), 1.f);
        const float za = zc(lo), zb = zc(lo + 1), zd = zc(lo + 2);
        const float bin0 = 0.5f * (za + zb), bin1 = 0.5f * (zb + zd);
        const float zs = fmaf(tt, bin1 - bin0, bin0);
        zsv[j] = zs;
        sZs[w][f] = zs;
    }
    __syncthreads();

    // ---------------- merge (LDS single source of truth -> provable bijection) --
    {   // coarse element: pos = lane + count(samples < z)
        int lo = 0, hi = 128;
        while (lo < hi) { const int mid = (lo + hi) >> 1; if (sZs[w][mid] < z) lo = mid + 1; else hi = mid; }
        sZf[w][lane + lo] = z;
    }
#pragma unroll
    for (int j = 0; j < 2; ++j) {   // sample element: pos = idx + count(coarse <= bv)
        const float bv = zsv[j];
        const int f = lane * 2 + j;
        int lo = 0, hi = 64;
        while (lo < hi) { const int mid = (lo + hi) >> 1; if (sZc[w][mid] <= bv) lo = mid + 1; else hi = mid; }
        sZf[w][f + lo] = bv;
    }
    __syncthreads();

    // ---------------- fine pass: 3 samples/lane ----------------
    const float zf0 = sZf[w][3 * lane + 0];
    const float zf1 = sZf[w][3 * lane + 1];
    const float zf2 = sZf[w][3 * lane + 2];
    const float zn2 = sZf[w][min(3 * lane + 3, 191)];      // lane63 value unused

    const v2f zA = mk2(zf0, zf0), zB = mk2(zf1, zf1), zC = mk2(zf2, zf2);
    v2f a01 = mk2(bb0, bb1), a23 = mk2(bb2, bb3);
    v2f e01 = mk2(bb0, bb1), e23 = mk2(bb2, bb3);
    v2f f01 = mk2(bb0, bb1), f23 = mk2(bb2, bb3);
#pragma unroll 2
    for (int i = 0; i < 16; ++i) {
        const float4 a4 = ABa[i];
        const float4 b4 = ABb[i];
        const float4 q0 = W2v[4 * i + 0], q1 = W2v[4 * i + 1];
        const float4 q2 = W2v[4 * i + 2], q3 = W2v[4 * i + 3];
        const v2f blo = mk2(b4.x, b4.y), bhi = mk2(b4.z, b4.w);
        const v2f alo = mk2(a4.x, a4.y), ahi = mk2(a4.z, a4.w);
        const v2f hAL = pmax0(pfma(zA, blo, alo)), hAH = pmax0(pfma(zA, bhi, ahi));
        const v2f hBL = pmax0(pfma(zB, blo, alo)), hBH = pmax0(pfma(zB, bhi, ahi));
        const v2f hCL = pmax0(pfma(zC, blo, alo)), hCH = pmax0(pfma(zC, bhi, ahi));
        const v2f q0a = mk2(q0.x, q0.y), q0b = mk2(q0.z, q0.w);
        const v2f q1a = mk2(q1.x, q1.y), q1b = mk2(q1.z, q1.w);
        const v2f q2a = mk2(q2.x, q2.y), q2b = mk2(q2.z, q2.w);
        const v2f q3a = mk2(q3.x, q3.y), q3b = mk2(q3.z, q3.w);
        a01 = pfma(mk2(hAL.x, hAL.x), q0a, a01); a23 = pfma(mk2(hAL.x, hAL.x), q0b, a23);
        a01 = pfma(mk2(hAL.y, hAL.y), q1a, a01); a23 = pfma(mk2(hAL.y, hAL.y), q1b, a23);
        a01 = pfma(mk2(hAH.x, hAH.x), q2a, a01); a23 = pfma(mk2(hAH.x, hAH.x), q2b, a23);
        a01 = pfma(mk2(hAH.y, hAH.y), q3a, a01); a23 = pfma(mk2(hAH.y, hAH.y), q3b, a23);
        e01 = pfma(mk2(hBL.x, hBL.x), q0a, e01); e23 = pfma(mk2(hBL.x, hBL.x), q0b, e23);
        e01 = pfma(mk2(hBL.y, hBL.y), q1a, e01); e23 = pfma(mk2(hBL.y, hBL.y), q1b, e23);
        e01 = pfma(mk2(hBH.x, hBH.x), q2a, e01); e23 = pfma(mk2(hBH.x, hBH.x), q2b, e23);
        e01 = pfma(mk2(hBH.y, hBH.y), q3a, e01); e23 = pfma(mk2(hBH.y, hBH.y), q3b, e23);
        f01 = pfma(mk2(hCL.x, hCL.x), q0a, f01); f23 = pfma(mk2(hCL.x, hCL.x), q0b, f23);
        f01 = pfma(mk2(hCL.y, hCL.y), q1a, f01); f23 = pfma(mk2(hCL.y, hCL.y), q1b, f23);
        f01 = pfma(mk2(hCH.x, hCH.x), q2a, f01); f23 = pfma(mk2(hCH.x, hCH.x), q2b, f23);
        f01 = pfma(mk2(hCH.y, hCH.y), q3a, f01); f23 = pfma(mk2(hCH.y, hCH.y), q3b, f23);
    }
    const float r0s = sigm(a01.x), g0s = sigm(a01.y), b0s = sigm(a23.x), s0 = fmaxf(a23.y, 0.f);
    const float r1s = sigm(e01.x), g1s = sigm(e01.y), b1s = sigm(e23.x), s1 = fmaxf(e23.y, 0.f);
    const float r2s = sigm(f01.x), g2s = sigm(f01.y), b2s = sigm(f23.x), s2 = fmaxf(f23.y, 0.f);

    const float d0 = (zf1 - zf0) * norm, d1 = (zf2 - zf1) * norm, d2 = (zn2 - zf2) * norm;
    const float al0 = 1.f - __expf(-s0 * d0);
    const float al1 = 1.f - __expf(-s1 * d1);
    const float al2 = (lane < 63) ? (1.f - __expf(-s2 * d2)) : 1.f;
    const float v0 = 1.f - al0 + EPS_T, v1 = 1.f - al1 + EPS_T, v2 = 1.f - al2 + EPS_T;

    float lp = v0 * v1 * v2;
#pragma unroll
    for (int off = 1; off < 64; off <<= 1) {               // product scan of lane products
        const float q = __shfl_up(lp, off);
        if (lane >= off) lp *= q;
    }
    float ex = __shfl_up(lp, 1);
    if (lane == 0) ex = 1.f;
    const float tr1 = ex * v0, tr2 = tr1 * v1;
    const float w0 = al0 * ex, w1 = al1 * tr1, w2 = al2 * tr2;

    // fine acc == 1 + O(192*EPS_T) -> white-bkgd term ~0
    float fr = fmaf(w0, r0s, fmaf(w1, r1s, w2 * r2s));
    float fg = fmaf(w0, g0s, fmaf(w1, g1s, w2 * g2s));
    float fb = fmaf(w0, b0s, fmaf(w1, b1s, w2 * b2s));
    float fd = fmaf(w0, zf0, fmaf(w1, zf1, w2 * zf2));
#pragma unroll
    for (int m = 1; m < 64; m <<= 1) {
        fr += __shfl_xor(fr, m); fg += __shfl_xor(fg, m);
        fb += __shfl_xor(fb, m); fd += __shfl_xor(fd, m);
    }

    if (lane == 0) {
        float* po = out + (size_t)ray * 8;
        po[0] = sr; po[1] = sg; po[2] = sb; po[3] = sd;
        po[4] = fr; po[5] = fg; po[6] = fb; po[7] = fd;
    }
}

extern "C" void kernel_launch(void* const* d_in, const int* in_sizes, int n_in,
                              void* d_out, int out_size, void* d_ws, size_t ws_size,
                              hipStream_t stream) {
    const float* ro = (const float*)d_in[0];
    const float* rd = (const float*)d_in[1];
    const float* W1 = (const float*)d_in[2];
    const float* b1 = (const float*)d_in[3];
    const float* W2 = (const float*)d_in[4];
    const float* b2 = (const float*)d_in[5];
    float* out = (float*)d_out;
    float* ws  = (float*)d_ws;    // needs 8192*128*4 = 4 MB; harness provides >=256 MB
    nerf_kernel<<<dim3(RAYS / 4), dim3(256), 0, stream>>>(ro, rd, W1, b1, W2, b2, out, ws);
}

// Round 7
// 90.296 us; speedup vs baseline: 1.0067x; 1.0067x over previous
//
#include <hip/hip_runtime.h>
#include <math.h>

// One wave per ray, 4 rays/block. Exactly R5 (verified) + ONE change:
// packed fp32 (v_pk_fma_f32 / v_pk_max_f32) in both MLP loops.
// A/B stay in LDS (ds_read_b128 broadcasts); W2 wave-uniform from global.
// Scans, CDF, sampling, LDS-single-source-of-truth merge: byte-identical to R5.

#define RAYS   8192
#define NEARP  2.0f
#define FARP   6.0f
#define EPS_T  1e-10f
#define EPS_W  1e-5f
#define F32EPS 1.1920929e-7f

typedef float v2f __attribute__((ext_vector_type(2)));
__device__ __forceinline__ v2f mk2(float a, float b) { v2f r; r.x = a; r.y = b; return r; }
__device__ __forceinline__ v2f pfma(v2f a, v2f b, v2f c) { return __builtin_elementwise_fma(a, b, c); }
__device__ __forceinline__ v2f pmax0(v2f a) { return __builtin_elementwise_max(a, mk2(0.f, 0.f)); }

__device__ __forceinline__ float zc(int i) {
    const float t = (float)i * (1.0f / 63.0f);
    return NEARP * (1.0f - t) + FARP * t;
}
__device__ __forceinline__ float sigm(float x) { return 1.f / (1.f + __expf(-x)); }

__global__ __launch_bounds__(256) void nerf_kernel(
    const float* __restrict__ ro, const float* __restrict__ rd,
    const float* __restrict__ W1, const float* __restrict__ b1,
    const float* __restrict__ W2, const float* __restrict__ b2,
    float* __restrict__ out)
{
    __shared__ __align__(16) float sA[4][64];
    __shared__ __align__(16) float sB[4][64];
    __shared__ float sCdf[4][64];    // 63 used
    __shared__ float sZc [4][64];    // coarse z grid (single source of truth for merge)
    __shared__ float sZs [4][128];   // fine z samples (sorted)
    __shared__ float sZf [4][192];   // merged

    const int tid  = threadIdx.x;
    const int w    = tid >> 6;
    const int lane = tid & 63;
    const int ray  = blockIdx.x * 4 + w;

    const float ox = ro[ray * 3 + 0], oy = ro[ray * 3 + 1], oz = ro[ray * 3 + 2];
    const float dx = rd[ray * 3 + 0], dy = rd[ray * 3 + 1], dz = rd[ray * 3 + 2];
    const float norm = sqrtf(dx * dx + dy * dy + dz * dz);
    const float inv  = 1.f / norm;
    const float vx = dx * inv, vy = dy * inv, vz = dz * inv;

    // ---- per-ray A/B precompute: lane h ----
    {
        const float w10 = W1[lane],       w11 = W1[64 + lane],  w12 = W1[128 + lane];
        const float w13 = W1[192 + lane], w14 = W1[256 + lane], w15 = W1[320 + lane];
        float A = b1[lane];
        A = fmaf(vz, w15, A); A = fmaf(vy, w14, A); A = fmaf(vx, w13, A);
        A = fmaf(oz, w12, A); A = fmaf(oy, w11, A); A = fmaf(ox, w10, A);
        const float B = fmaf(dx, w10, fmaf(dy, w11, dz * w12));
        sA[w][lane] = A; sB[w][lane] = B;
    }
    __syncthreads();

    const float4* W2v = (const float4*)W2;
    const float bb0 = b2[0], bb1 = b2[1], bb2 = b2[2], bb3 = b2[3];

    // ---------------- coarse pass ----------------
    const float z = zc(lane);
    sZc[w][lane] = z;
    const v2f zz = mk2(z, z);
    v2f o01 = mk2(bb0, bb1), o23 = mk2(bb2, bb3);
#pragma unroll 4
    for (int i = 0; i < 16; ++i) {
        const float4 a4 = ((const float4*)sA[w])[i];
        const float4 b4 = ((const float4*)sB[w])[i];
        const float4 q0 = W2v[4 * i + 0], q1 = W2v[4 * i + 1];
        const float4 q2 = W2v[4 * i + 2], q3 = W2v[4 * i + 3];
        const v2f hL = pmax0(pfma(zz, mk2(b4.x, b4.y), mk2(a4.x, a4.y)));
        const v2f hH = pmax0(pfma(zz, mk2(b4.z, b4.w), mk2(a4.z, a4.w)));
        o01 = pfma(mk2(hL.x, hL.x), mk2(q0.x, q0.y), o01);
        o23 = pfma(mk2(hL.x, hL.x), mk2(q0.z, q0.w), o23);
        o01 = pfma(mk2(hL.y, hL.y), mk2(q1.x, q1.y), o01);
        o23 = pfma(mk2(hL.y, hL.y), mk2(q1.z, q1.w), o23);
        o01 = pfma(mk2(hH.x, hH.x), mk2(q2.x, q2.y), o01);
        o23 = pfma(mk2(hH.x, hH.x), mk2(q2.z, q2.w), o23);
        o01 = pfma(mk2(hH.y, hH.y), mk2(q3.x, q3.y), o01);
        o23 = pfma(mk2(hH.y, hH.y), mk2(q3.z, q3.w), o23);
    }
    const float r   = sigm(o01.x), g = sigm(o01.y), bl = sigm(o23.x);
    const float sig = fmaxf(o23.y, 0.f);

    // volrender (coarse)
    const float znext = __shfl_down(z, 1);                 // lane63 unused
    const float dist  = (znext - z) * norm;
    const float alpha = (lane < 63) ? (1.f - __expf(-sig * dist)) : 1.f;
    const float vfac  = 1.f - alpha + EPS_T;
    float p = vfac;
#pragma unroll
    for (int off = 1; off < 64; off <<= 1) {               // inclusive product scan
        const float q = __shfl_up(p, off);
        if (lane >= off) p *= q;
    }
    float excl = __shfl_up(p, 1);
    if (lane == 0) excl = 1.f;
    const float wgt = alpha * excl;

    // acc == 1 + O(64*EPS_T) (last alpha forced 1) -> white-bkgd term ~0
    float sr = wgt * r, sg = wgt * g, sb = wgt * bl, sd = wgt * z;
#pragma unroll
    for (int m = 1; m < 64; m <<= 1) {
        sr += __shfl_xor(sr, m); sg += __shfl_xor(sg, m);
        sb += __shfl_xor(sb, m); sd += __shfl_xor(sd, m);
    }

    // ---------------- inverse-CDF sampling ----------------
    const float wmraw = __shfl_down(wgt, 1);
    const float wmv   = (lane < 62) ? wmraw : 0.f;          // weights[:,1:-1], 62 bins
    float wsum = wmv;
#pragma unroll
    for (int m = 1; m < 64; m <<= 1) wsum += __shfl_xor(wsum, m);
    const float pad  = fmaxf(0.f, EPS_W - wsum);
    const float wadj = wmv + pad * (1.0f / 62.0f);
    const float wsp  = wsum + pad;
    const float pdf  = (lane < 62) ? (wadj / wsp) : 0.f;
    float ps = pdf;
#pragma unroll
    for (int off = 1; off < 64; off <<= 1) {               // inclusive sum scan
        const float q = __shfl_up(ps, off);
        if (lane >= off) ps += q;
    }
    if (lane < 61)  sCdf[w][lane + 1] = fminf(1.f, ps);    // cdf[1..61]
    if (lane == 61) sCdf[w][0]  = 0.f;
    if (lane == 62) sCdf[w][62] = 1.f;
    __syncthreads();

    float zsv[2];
#pragma unroll
    for (int j = 0; j < 2; ++j) {
        const int f = lane * 2 + j;
        const float u = (float)f * ((1.0f - F32EPS) / 127.0f);
        int lo = 0, hi = 62;                               // cdf[0]=0<=u < 1=cdf[62]
        while (hi - lo > 1) {
            const int mid = (lo + hi) >> 1;
            if (sCdf[w][mid] <= u) lo = mid; else hi = mid;
        }
        const float c0 = sCdf[w][lo], c1 = sCdf[w][lo + 1];
        const float den = c1 - c0;
        float tt = (den > 0.f) ? (u - c0) / den : 0.f;
        tt = fminf(fmaxf(tt, 0.f), 1.f);
        const float za = zc(lo), zb = zc(lo + 1), zd = zc(lo + 2);
        const float bin0 = 0.5f * (za + zb), bin1 = 0.5f * (zb + zd);
        const float zs = fmaf(tt, bin1 - bin0, bin0);
        zsv[j] = zs;
        sZs[w][f] = zs;
    }
    __syncthreads();

    // ---------------- merge (LDS single source of truth -> provable bijection) --
    {   // coarse element: pos = lane + count(samples < z)
        int lo = 0, hi = 128;
        while (lo < hi) { const int mid = (lo + hi) >> 1; if (sZs[w][mid] < z) lo = mid + 1; else hi = mid; }
        sZf[w][lane + lo] = z;
    }
#pragma unroll
    for (int j = 0; j < 2; ++j) {   // sample element: pos = idx + count(coarse <= bv)
        const float bv = zsv[j];
        const int f = lane * 2 + j;
        int lo = 0, hi = 64;
        while (lo < hi) { const int mid = (lo + hi) >> 1; if (sZc[w][mid] <= bv) lo = mid + 1; else hi = mid; }
        sZf[w][f + lo] = bv;
    }
    __syncthreads();

    // ---------------- fine pass: 3 samples/lane ----------------
    const float zf0 = sZf[w][3 * lane + 0];
    const float zf1 = sZf[w][3 * lane + 1];
    const float zf2 = sZf[w][3 * lane + 2];
    const float zn2 = sZf[w][min(3 * lane + 3, 191)];      // lane63 value unused

    const v2f zA = mk2(zf0, zf0), zB = mk2(zf1, zf1), zC = mk2(zf2, zf2);
    v2f a01 = mk2(bb0, bb1), a23 = mk2(bb2, bb3);
    v2f e01 = mk2(bb0, bb1), e23 = mk2(bb2, bb3);
    v2f f01 = mk2(bb0, bb1), f23 = mk2(bb2, bb3);
#pragma unroll 2
    for (int i = 0; i < 16; ++i) {
        const float4 a4 = ((const float4*)sA[w])[i];
        const float4 b4 = ((const float4*)sB[w])[i];
        const float4 q0 = W2v[4 * i + 0], q1 = W2v[4 * i + 1];
        const float4 q2 = W2v[4 * i + 2], q3 = W2v[4 * i + 3];
        const v2f blo = mk2(b4.x, b4.y), bhi = mk2(b4.z, b4.w);
        const v2f alo = mk2(a4.x, a4.y), ahi = mk2(a4.z, a4.w);
        const v2f hAL = pmax0(pfma(zA, blo, alo)), hAH = pmax0(pfma(zA, bhi, ahi));
        const v2f hBL = pmax0(pfma(zB, blo, alo)), hBH = pmax0(pfma(zB, bhi, ahi));
        const v2f hCL = pmax0(pfma(zC, blo, alo)), hCH = pmax0(pfma(zC, bhi, ahi));
        const v2f q0a = mk2(q0.x, q0.y), q0b = mk2(q0.z, q0.w);
        const v2f q1a = mk2(q1.x, q1.y), q1b = mk2(q1.z, q1.w);
        const v2f q2a = mk2(q2.x, q2.y), q2b = mk2(q2.z, q2.w);
        const v2f q3a = mk2(q3.x, q3.y), q3b = mk2(q3.z, q3.w);
        a01 = pfma(mk2(hAL.x, hAL.x), q0a, a01); a23 = pfma(mk2(hAL.x, hAL.x), q0b, a23);
        a01 = pfma(mk2(hAL.y, hAL.y), q1a, a01); a23 = pfma(mk2(hAL.y, hAL.y), q1b, a23);
        a01 = pfma(mk2(hAH.x, hAH.x), q2a, a01); a23 = pfma(mk2(hAH.x, hAH.x), q2b, a23);
        a01 = pfma(mk2(hAH.y, hAH.y), q3a, a01); a23 = pfma(mk2(hAH.y, hAH.y), q3b, a23);
        e01 = pfma(mk2(hBL.x, hBL.x), q0a, e01); e23 = pfma(mk2(hBL.x, hBL.x), q0b, e23);
        e01 = pfma(mk2(hBL.y, hBL.y), q1a, e01); e23 = pfma(mk2(hBL.y, hBL.y), q1b, e23);
        e01 = pfma(mk2(hBH.x, hBH.x), q2a, e01); e23 = pfma(mk2(hBH.x, hBH.x), q2b, e23);
        e01 = pfma(mk2(hBH.y, hBH.y), q3a, e01); e23 = pfma(mk2(hBH.y, hBH.y), q3b, e23);
        f01 = pfma(mk2(hCL.x, hCL.x), q0a, f01); f23 = pfma(mk2(hCL.x, hCL.x), q0b, f23);
        f01 = pfma(mk2(hCL.y, hCL.y), q1a, f01); f23 = pfma(mk2(hCL.y, hCL.y), q1b, f23);
        f01 = pfma(mk2(hCH.x, hCH.x), q2a, f01); f23 = pfma(mk2(hCH.x, hCH.x), q2b, f23);
        f01 = pfma(mk2(hCH.y, hCH.y), q3a, f01); f23 = pfma(mk2(hCH.y, hCH.y), q3b, f23);
    }
    const float r0s = sigm(a01.x), g0s = sigm(a01.y), b0s = sigm(a23.x), s0 = fmaxf(a23.y, 0.f);
    const float r1s = sigm(e01.x), g1s = sigm(e01.y), b1s = sigm(e23.x), s1 = fmaxf(e23.y, 0.f);
    const float r2s = sigm(f01.x), g2s = sigm(f01.y), b2s = sigm(f23.x), s2 = fmaxf(f23.y, 0.f);

    const float d0 = (zf1 - zf0) * norm, d1 = (zf2 - zf1) * norm, d2 = (zn2 - zf2) * norm;
    const float al0 = 1.f - __expf(-s0 * d0);
    const float al1 = 1.f - __expf(-s1 * d1);
    const float al2 = (lane < 63) ? (1.f - __expf(-s2 * d2)) : 1.f;
    const float v0 = 1.f - al0 + EPS_T, v1 = 1.f - al1 + EPS_T, v2 = 1.f - al2 + EPS_T;

    float lp = v0 * v1 * v2;
#pragma unroll
    for (int off = 1; off < 64; off <<= 1) {               // product scan of lane products
        const float q = __shfl_up(lp, off);
        if (lane >= off) lp *= q;
    }
    float ex = __shfl_up(lp, 1);
    if (lane == 0) ex = 1.f;
    const float tr1 = ex * v0, tr2 = tr1 * v1;
    const float w0 = al0 * ex, w1 = al1 * tr1, w2 = al2 * tr2;

    // fine acc == 1 + O(192*EPS_T) -> white-bkgd term ~0
    float fr = fmaf(w0, r0s, fmaf(w1, r1s, w2 * r2s));
    float fg = fmaf(w0, g0s, fmaf(w1, g1s, w2 * g2s));
    float fb = fmaf(w0, b0s, fmaf(w1, b1s, w2 * b2s));
    float fd = fmaf(w0, zf0, fmaf(w1, zf1, w2 * zf2));
#pragma unroll
    for (int m = 1; m < 64; m <<= 1) {
        fr += __shfl_xor(fr, m); fg += __shfl_xor(fg, m);
        fb += __shfl_xor(fb, m); fd += __shfl_xor(fd, m);
    }

    if (lane == 0) {
        float* po = out + (size_t)ray * 8;
        po[0] = sr; po[1] = sg; po[2] = sb; po[3] = sd;
        po[4] = fr; po[5] = fg; po[6] = fb; po[7] = fd;
    }
}

extern "C" void kernel_launch(void* const* d_in, const int* in_sizes, int n_in,
                              void* d_out, int out_size, void* d_ws, size_t ws_size,
                              hipStream_t stream) {
    const float* ro = (const float*)d_in[0];
    const float* rd = (const float*)d_in[1];
    const float* W1 = (const float*)d_in[2];
    const float* b1 = (const float*)d_in[3];
    const float* W2 = (const float*)d_in[4];
    const float* b2 = (const float*)d_in[5];
    float* out = (float*)d_out;
    nerf_kernel<<<dim3(RAYS / 4), dim3(256), 0, stream>>>(ro, rd, W1, b1, W2, b2, out);
}

// Round 8
// 85.693 us; speedup vs baseline: 1.0608x; 1.0537x over previous
//
#include <hip/hip_runtime.h>
#include <math.h>

// One wave per ray, 4 rays/block. R7-verified skeleton + two changes:
// (1) Coarse-MLP reuse: z_fine = merge(coarse z, samples); the 64 coarse points
//     are re-evaluated bit-identically by the reference fine pass, so we store
//     coarse (r,g,b,sigma) and only run the fine MLP on the 128 fresh samples
//     (2/lane instead of 3/lane) -> deletes 25% of MLP FLOPs, zero numerics delta.
//     Values routed through the merge bijection via sVal[pos] (float4 in LDS).
// (2) All LDS is per-wave -> replace __syncthreads (cross-wave convoy) with
//     intra-wave s_waitcnt lgkmcnt(0) + wave_barrier (wave64 lockstep).
// sCdf aliases the sVal pool (dead before first sVal write) -> LDS 20480 B/block,
// still 8 blocks/CU.

#define RAYS   8192
#define NEARP  2.0f
#define FARP   6.0f
#define EPS_T  1e-10f
#define EPS_W  1e-5f
#define F32EPS 1.1920929e-7f

typedef float v2f __attribute__((ext_vector_type(2)));
__device__ __forceinline__ v2f mk2(float a, float b) { v2f r; r.x = a; r.y = b; return r; }
__device__ __forceinline__ v2f pfma(v2f a, v2f b, v2f c) { return __builtin_elementwise_fma(a, b, c); }
__device__ __forceinline__ v2f pmax0(v2f a) { return __builtin_elementwise_max(a, mk2(0.f, 0.f)); }

__device__ __forceinline__ float zc(int i) {
    const float t = (float)i * (1.0f / 63.0f);
    return NEARP * (1.0f - t) + FARP * t;
}
__device__ __forceinline__ float sigm(float x) { return 1.f / (1.f + __expf(-x)); }

// intra-wave LDS sync: wave64 is lockstep; asm memory clobber stops compiler
// reordering, waitcnt drains DS ops, wave_barrier pins the scheduler.
__device__ __forceinline__ void wsync() {
    __asm__ __volatile__("s_waitcnt lgkmcnt(0)" ::: "memory");
    __builtin_amdgcn_wave_barrier();
}

__global__ __launch_bounds__(256) void nerf_kernel(
    const float* __restrict__ ro, const float* __restrict__ rd,
    const float* __restrict__ W1, const float* __restrict__ b1,
    const float* __restrict__ W2, const float* __restrict__ b2,
    float* __restrict__ out)
{
    __shared__ __align__(16) float sA[4][64];
    __shared__ __align__(16) float sB[4][64];
    __shared__ float sZc [4][64];    // coarse z grid (single source of truth for merge)
    __shared__ float sZs [4][128];   // fine z samples (sorted)
    __shared__ float sZf [4][192];   // merged z
    __shared__ __align__(16) char sPool[4][192 * 16];  // sCdf (early) / sVal (late)

    const int tid  = threadIdx.x;
    const int w    = tid >> 6;
    const int lane = tid & 63;
    const int ray  = blockIdx.x * 4 + w;

    float*  sCdfw = (float*)&sPool[w][0];    // 63 floats used, dead after sampling
    float4* sValw = (float4*)&sPool[w][0];   // 192 float4, live from merge on

    const float ox = ro[ray * 3 + 0], oy = ro[ray * 3 + 1], oz = ro[ray * 3 + 2];
    const float dx = rd[ray * 3 + 0], dy = rd[ray * 3 + 1], dz = rd[ray * 3 + 2];
    const float norm = sqrtf(dx * dx + dy * dy + dz * dz);
    const float inv  = 1.f / norm;
    const float vx = dx * inv, vy = dy * inv, vz = dz * inv;

    // ---- per-ray A/B precompute: lane h ----
    {
        const float w10 = W1[lane],       w11 = W1[64 + lane],  w12 = W1[128 + lane];
        const float w13 = W1[192 + lane], w14 = W1[256 + lane], w15 = W1[320 + lane];
        float A = b1[lane];
        A = fmaf(vz, w15, A); A = fmaf(vy, w14, A); A = fmaf(vx, w13, A);
        A = fmaf(oz, w12, A); A = fmaf(oy, w11, A); A = fmaf(ox, w10, A);
        const float B = fmaf(dx, w10, fmaf(dy, w11, dz * w12));
        sA[w][lane] = A; sB[w][lane] = B;
    }
    wsync();

    const float4* W2v = (const float4*)W2;
    const float bb0 = b2[0], bb1 = b2[1], bb2 = b2[2], bb3 = b2[3];

    // ---------------- coarse pass ----------------
    const float z = zc(lane);
    sZc[w][lane] = z;
    const v2f zz = mk2(z, z);
    v2f o01 = mk2(bb0, bb1), o23 = mk2(bb2, bb3);
#pragma unroll 4
    for (int i = 0; i < 16; ++i) {
        const float4 a4 = ((const float4*)sA[w])[i];
        const float4 b4 = ((const float4*)sB[w])[i];
        const float4 q0 = W2v[4 * i + 0], q1 = W2v[4 * i + 1];
        const float4 q2 = W2v[4 * i + 2], q3 = W2v[4 * i + 3];
        const v2f hL = pmax0(pfma(zz, mk2(b4.x, b4.y), mk2(a4.x, a4.y)));
        const v2f hH = pmax0(pfma(zz, mk2(b4.z, b4.w), mk2(a4.z, a4.w)));
        o01 = pfma(mk2(hL.x, hL.x), mk2(q0.x, q0.y), o01);
        o23 = pfma(mk2(hL.x, hL.x), mk2(q0.z, q0.w), o23);
        o01 = pfma(mk2(hL.y, hL.y), mk2(q1.x, q1.y), o01);
        o23 = pfma(mk2(hL.y, hL.y), mk2(q1.z, q1.w), o23);
        o01 = pfma(mk2(hH.x, hH.x), mk2(q2.x, q2.y), o01);
        o23 = pfma(mk2(hH.x, hH.x), mk2(q2.z, q2.w), o23);
        o01 = pfma(mk2(hH.y, hH.y), mk2(q3.x, q3.y), o01);
        o23 = pfma(mk2(hH.y, hH.y), mk2(q3.z, q3.w), o23);
    }
    const float r   = sigm(o01.x), g = sigm(o01.y), bl = sigm(o23.x);
    const float sig = fmaxf(o23.y, 0.f);

    // volrender (coarse)
    const float znext = __shfl_down(z, 1);                 // lane63 unused
    const float dist  = (znext - z) * norm;
    const float alpha = (lane < 63) ? (1.f - __expf(-sig * dist)) : 1.f;
    const float vfac  = 1.f - alpha + EPS_T;
    float p = vfac;
#pragma unroll
    for (int off = 1; off < 64; off <<= 1) {               // inclusive product scan
        const float q = __shfl_up(p, off);
        if (lane >= off) p *= q;
    }
    float excl = __shfl_up(p, 1);
    if (lane == 0) excl = 1.f;
    const float wgt = alpha * excl;

    // acc == 1 + O(64*EPS_T) (last alpha forced 1) -> white-bkgd term ~0
    float sr = wgt * r, sg = wgt * g, sb = wgt * bl, sd = wgt * z;
#pragma unroll
    for (int m = 1; m < 64; m <<= 1) {
        sr += __shfl_xor(sr, m); sg += __shfl_xor(sg, m);
        sb += __shfl_xor(sb, m); sd += __shfl_xor(sd, m);
    }

    // ---------------- inverse-CDF sampling ----------------
    const float wmraw = __shfl_down(wgt, 1);
    const float wmv   = (lane < 62) ? wmraw : 0.f;          // weights[:,1:-1], 62 bins
    float wsum = wmv;
#pragma unroll
    for (int m = 1; m < 64; m <<= 1) wsum += __shfl_xor(wsum, m);
    const float pad  = fmaxf(0.f, EPS_W - wsum);
    const float wadj = wmv + pad * (1.0f / 62.0f);
    const float wsp  = wsum + pad;
    const float pdf  = (lane < 62) ? (wadj / wsp) : 0.f;
    float ps = pdf;
#pragma unroll
    for (int off = 1; off < 64; off <<= 1) {               // inclusive sum scan
        const float q = __shfl_up(ps, off);
        if (lane >= off) ps += q;
    }
    if (lane < 61)  sCdfw[lane + 1] = fminf(1.f, ps);      // cdf[1..61]
    if (lane == 61) sCdfw[0]  = 0.f;
    if (lane == 62) sCdfw[62] = 1.f;
    wsync();

    float zsv[2];
#pragma unroll
    for (int j = 0; j < 2; ++j) {
        const int f = lane * 2 + j;
        const float u = (float)f * ((1.0f - F32EPS) / 127.0f);
        int lo = 0, hi = 62;                               // cdf[0]=0<=u < 1=cdf[62]
        while (hi - lo > 1) {
            const int mid = (lo + hi) >> 1;
            if (sCdfw[mid] <= u) lo = mid; else hi = mid;
        }
        const float c0 = sCdfw[lo], c1 = sCdfw[lo + 1];
        const float den = c1 - c0;
        float tt = (den > 0.f) ? (u - c0) / den : 0.f;
        tt = fminf(fmaxf(tt, 0.f), 1.f);
        const float za = zc(lo), zb = zc(lo + 1), zd = zc(lo + 2);
        const float bin0 = 0.5f * (za + zb), bin1 = 0.5f * (zb + zd);
        const float zs = fmaf(tt, bin1 - bin0, bin0);
        zsv[j] = zs;
        sZs[w][f] = zs;
    }
    wsync();   // sCdf reads done; sVal (same pool) may be written after this point

    // ---------------- fresh-sample MLP (2 samples/lane) ----------------
    const v2f zA = mk2(zsv[0], zsv[0]), zB = mk2(zsv[1], zsv[1]);
    v2f a01 = mk2(bb0, bb1), a23 = mk2(bb2, bb3);
    v2f e01 = mk2(bb0, bb1), e23 = mk2(bb2, bb3);
#pragma unroll 2
    for (int i = 0; i < 16; ++i) {
        const float4 a4 = ((const float4*)sA[w])[i];
        const float4 b4 = ((const float4*)sB[w])[i];
        const float4 q0 = W2v[4 * i + 0], q1 = W2v[4 * i + 1];
        const float4 q2 = W2v[4 * i + 2], q3 = W2v[4 * i + 3];
        const v2f blo = mk2(b4.x, b4.y), bhi = mk2(b4.z, b4.w);
        const v2f alo = mk2(a4.x, a4.y), ahi = mk2(a4.z, a4.w);
        const v2f hAL = pmax0(pfma(zA, blo, alo)), hAH = pmax0(pfma(zA, bhi, ahi));
        const v2f hBL = pmax0(pfma(zB, blo, alo)), hBH = pmax0(pfma(zB, bhi, ahi));
        const v2f q0a = mk2(q0.x, q0.y), q0b = mk2(q0.z, q0.w);
        const v2f q1a = mk2(q1.x, q1.y), q1b = mk2(q1.z, q1.w);
        const v2f q2a = mk2(q2.x, q2.y), q2b = mk2(q2.z, q2.w);
        const v2f q3a = mk2(q3.x, q3.y), q3b = mk2(q3.z, q3.w);
        a01 = pfma(mk2(hAL.x, hAL.x), q0a, a01); a23 = pfma(mk2(hAL.x, hAL.x), q0b, a23);
        a01 = pfma(mk2(hAL.y, hAL.y), q1a, a01); a23 = pfma(mk2(hAL.y, hAL.y), q1b, a23);
        a01 = pfma(mk2(hAH.x, hAH.x), q2a, a01); a23 = pfma(mk2(hAH.x, hAH.x), q2b, a23);
        a01 = pfma(mk2(hAH.y, hAH.y), q3a, a01); a23 = pfma(mk2(hAH.y, hAH.y), q3b, a23);
        e01 = pfma(mk2(hBL.x, hBL.x), q0a, e01); e23 = pfma(mk2(hBL.x, hBL.x), q0b, e23);
        e01 = pfma(mk2(hBL.y, hBL.y), q1a, e01); e23 = pfma(mk2(hBL.y, hBL.y), q1b, e23);
        e01 = pfma(mk2(hBH.x, hBH.x), q2a, e01); e23 = pfma(mk2(hBH.x, hBH.x), q2b, e23);
        e01 = pfma(mk2(hBH.y, hBH.y), q3a, e01); e23 = pfma(mk2(hBH.y, hBH.y), q3b, e23);
    }
    const float r0s = sigm(a01.x), g0s = sigm(a01.y), b0s = sigm(a23.x), s0 = fmaxf(a23.y, 0.f);
    const float r1s = sigm(e01.x), g1s = sigm(e01.y), b1s = sigm(e23.x), s1 = fmaxf(e23.y, 0.f);

    // ---------------- merge (LDS single source of truth -> provable bijection) --
    {   // coarse element: pos = lane + count(samples < z); carry coarse MLP values
        int lo = 0, hi = 128;
        while (lo < hi) { const int mid = (lo + hi) >> 1; if (sZs[w][mid] < z) lo = mid + 1; else hi = mid; }
        sZf[w][lane + lo] = z;
        float4 cv; cv.x = r; cv.y = g; cv.z = bl; cv.w = sig;
        sValw[lane + lo] = cv;
    }
#pragma unroll
    for (int j = 0; j < 2; ++j) {   // sample element: pos = idx + count(coarse <= bv)
        const float bv = zsv[j];
        const int f = lane * 2 + j;
        int lo = 0, hi = 64;
        while (lo < hi) { const int mid = (lo + hi) >> 1; if (sZc[w][mid] <= bv) lo = mid + 1; else hi = mid; }
        sZf[w][f + lo] = bv;
        float4 cv;
        if (j == 0) { cv.x = r0s; cv.y = g0s; cv.z = b0s; cv.w = s0; }
        else        { cv.x = r1s; cv.y = g1s; cv.z = b1s; cv.w = s1; }
        sValw[f + lo] = cv;
    }
    wsync();

    // ---------------- fine volrender: 3 positions/lane ----------------
    const float zf0 = sZf[w][3 * lane + 0];
    const float zf1 = sZf[w][3 * lane + 1];
    const float zf2 = sZf[w][3 * lane + 2];
    const float zn2 = sZf[w][min(3 * lane + 3, 191)];      // lane63 value unused
    const float4 c4a = sValw[3 * lane + 0];
    const float4 c4b = sValw[3 * lane + 1];
    const float4 c4c = sValw[3 * lane + 2];

    const float d0 = (zf1 - zf0) * norm, d1 = (zf2 - zf1) * norm, d2 = (zn2 - zf2) * norm;
    const float al0 = 1.f - __expf(-c4a.w * d0);
    const float al1 = 1.f - __expf(-c4b.w * d1);
    const float al2 = (lane < 63) ? (1.f - __expf(-c4c.w * d2)) : 1.f;
    const float t0v = 1.f - al0 + EPS_T, t1v = 1.f - al1 + EPS_T, t2v = 1.f - al2 + EPS_T;

    float lp = t0v * t1v * t2v;
#pragma unroll
    for (int off = 1; off < 64; off <<= 1) {               // product scan of lane products
        const float q = __shfl_up(lp, off);
        if (lane >= off) lp *= q;
    }
    float ex = __shfl_up(lp, 1);
    if (lane == 0) ex = 1.f;
    const float tr1 = ex * t0v, tr2 = tr1 * t1v;
    const float w0 = al0 * ex, w1 = al1 * tr1, w2 = al2 * tr2;

    // fine acc == 1 + O(192*EPS_T) -> white-bkgd term ~0
    float fr = fmaf(w0, c4a.x, fmaf(w1, c4b.x, w2 * c4c.x));
    float fg = fmaf(w0, c4a.y, fmaf(w1, c4b.y, w2 * c4c.y));
    float fb = fmaf(w0, c4a.z, fmaf(w1, c4b.z, w2 * c4c.z));
    float fd = fmaf(w0, zf0,   fmaf(w1, zf1,   w2 * zf2));
#pragma unroll
    for (int m = 1; m < 64; m <<= 1) {
        fr += __shfl_xor(fr, m); fg += __shfl_xor(fg, m);
        fb += __shfl_xor(fb, m); fd += __shfl_xor(fd, m);
    }

    if (lane == 0) {
        float* po = out + (size_t)ray * 8;
        po[0] = sr; po[1] = sg; po[2] = sb; po[3] = sd;
        po[4] = fr; po[5] = fg; po[6] = fb; po[7] = fd;
    }
}

extern "C" void kernel_launch(void* const* d_in, const int* in_sizes, int n_in,
                              void* d_out, int out_size, void* d_ws, size_t ws_size,
                              hipStream_t stream) {
    const float* ro = (const float*)d_in[0];
    const float* rd = (const float*)d_in[1];
    const float* W1 = (const float*)d_in[2];
    const float* b1 = (const float*)d_in[3];
    const float* W2 = (const float*)d_in[4];
    const float* b2 = (const float*)d_in[5];
    float* out = (float*)d_out;
    nerf_kernel<<<dim3(RAYS / 4), dim3(256), 0, stream>>>(ro, rd, W1, b1, W2, b2, out);
}